// Round 1
// baseline (1256.125 us; speedup 1.0000x reference)
//
#include <hip/hip_runtime.h>

#define HEADS 16
#define DH 64
#define BB 2
#define SEQ 2048
#define DMODEL 1024
#define ATTN_SCALE 0.125f  // 1/sqrt(64)

// ---------------------------------------------------------------------------
// Tiled fp32 GEMM: C = A[M,K] @ B[K,N] (+bias). 64x64 tile, BK=16, 256 thr,
// 4x4 micro-tile per thread.
// MODE 0: scatter output to head-major [b][h][seq][dh] (for Q/K/V proj)
// MODE 1: plain row-major + bias (for output projection)
// ---------------------------------------------------------------------------
template <int MODE>
__global__ __launch_bounds__(256) void gemm_tile(
    const float* __restrict__ A, const float* __restrict__ Bm,
    const float* __restrict__ bias, float* __restrict__ C,
    int M, int N, int K) {
  __shared__ float As[16][68];  // transposed: As[k][m], pad 68 breaks write conflicts
  __shared__ float Bs[16][68];

  const int t = threadIdx.x;
  const int tx = t & 15, ty = t >> 4;
  const int row0 = blockIdx.y * 64, col0 = blockIdx.x * 64;
  const int lr = t >> 2;          // A: row within tile
  const int lk4 = (t & 3) << 2;   // A: k offset (float4)
  const int lkb = t >> 4;         // B: k row
  const int lc4 = (t & 15) << 2;  // B: col offset (float4)

  float acc[4][4] = {};

  const float* Aptr = A + (size_t)(row0 + lr) * K + lk4;
  const float* Bptr = Bm + (size_t)lkb * N + col0 + lc4;

  for (int k0 = 0; k0 < K; k0 += 16) {
    const float4 a = *(const float4*)(Aptr + k0);
    const float4 b = *(const float4*)(Bptr + (size_t)k0 * N);
    __syncthreads();
    As[lk4 + 0][lr] = a.x;
    As[lk4 + 1][lr] = a.y;
    As[lk4 + 2][lr] = a.z;
    As[lk4 + 3][lr] = a.w;
    *(float4*)&Bs[lkb][lc4] = b;
    __syncthreads();
#pragma unroll
    for (int kk = 0; kk < 16; ++kk) {
      const float4 av = *(const float4*)&As[kk][ty * 4];
      const float4 bv = *(const float4*)&Bs[kk][tx * 4];
      const float ar[4] = {av.x, av.y, av.z, av.w};
      const float br[4] = {bv.x, bv.y, bv.z, bv.w};
#pragma unroll
      for (int i = 0; i < 4; ++i)
#pragma unroll
        for (int j = 0; j < 4; ++j)
          acc[i][j] = fmaf(ar[i], br[j], acc[i][j]);
    }
  }

  if (MODE == 0) {
    // head-major scatter: col -> (h, dh); tile cols are 64-aligned so h fixed
    const int cb = col0 + tx * 4;
    const int h = cb >> 6, dd = cb & 63;
#pragma unroll
    for (int i = 0; i < 4; ++i) {
      const int r = row0 + ty * 4 + i;
      const int bidx = r >> 11, s = r & (SEQ - 1);
      const float4 val = make_float4(acc[i][0], acc[i][1], acc[i][2], acc[i][3]);
      *(float4*)&C[((((size_t)bidx * HEADS + h) * SEQ) + s) * DH + dd] = val;
    }
  } else {
    const int cb = col0 + tx * 4;
    const float4 bi = *(const float4*)&bias[cb];
#pragma unroll
    for (int i = 0; i < 4; ++i) {
      const int r = row0 + ty * 4 + i;
      const float4 val = make_float4(acc[i][0] + bi.x, acc[i][1] + bi.y,
                                     acc[i][2] + bi.z, acc[i][3] + bi.w);
      *(float4*)&C[(size_t)r * N + cb] = val;
    }
  }
}

// ---------------------------------------------------------------------------
// Flash attention, fp32. One block = (b,h) pair x 64-row Q tile. 256 threads,
// each owns a 4x4 tile of S (rows=queries, cols=keys) and a 4x4 tile of O
// (rows=queries, cols=dh). Online softmax, K-tiles of 64.
// LDS: QsT[d][i], Vs[j][d], sKP = union{ KsT[d][j] (stride 64), Ps[i][j]
// (stride 68) } -> ~50 KB total, 3 blocks/CU.
// ---------------------------------------------------------------------------
__global__ __launch_bounds__(256) void flash_attn(
    const float* __restrict__ Qg, const float* __restrict__ Kg,
    const float* __restrict__ Vg, float* __restrict__ Og) {
  __shared__ float QsT[64][64];
  __shared__ float Vs[64 * 64];
  __shared__ float sKP[64 * 68];

  const int t = threadIdx.x;
  const int tx = t & 15, ty = t >> 4;
  const int qt = blockIdx.x;  // 0..31 q tile
  const int bh = blockIdx.y;  // 0..31 (b*16+h)

  const float* qp = Qg + ((size_t)bh * SEQ + qt * 64) * DH;
  const float* kp = Kg + (size_t)bh * SEQ * DH;
  const float* vp = Vg + (size_t)bh * SEQ * DH;

  // load Q tile transposed: QsT[d][i]
#pragma unroll
  for (int rep = 0; rep < 4; ++rep) {
    const int u = t + rep * 256;       // float4 index into 64x64 tile
    const int i = u >> 4;              // row (query)
    const int d = (u & 15) << 2;       // dh offset
    const float4 qq = ((const float4*)qp)[u];
    QsT[d + 0][i] = qq.x;
    QsT[d + 1][i] = qq.y;
    QsT[d + 2][i] = qq.z;
    QsT[d + 3][i] = qq.w;
  }

  float m_i[4], l_i[4], Oacc[4][4];
#pragma unroll
  for (int i = 0; i < 4; ++i) {
    m_i[i] = -1e30f;
    l_i[i] = 0.f;
#pragma unroll
    for (int j = 0; j < 4; ++j) Oacc[i][j] = 0.f;
  }

  for (int kt = 0; kt < SEQ / 64; ++kt) {
    const float* ktile = kp + (size_t)kt * 64 * DH;
    const float* vtile = vp + (size_t)kt * 64 * DH;
    float4 kreg[4], vreg[4];
#pragma unroll
    for (int rep = 0; rep < 4; ++rep) {
      kreg[rep] = ((const float4*)ktile)[t + rep * 256];
      vreg[rep] = ((const float4*)vtile)[t + rep * 256];
    }
    __syncthreads();  // prior iter's reads of sKP/Vs complete
#pragma unroll
    for (int rep = 0; rep < 4; ++rep) {
      const int u = t + rep * 256;
      const int j = u >> 4;
      const int d = (u & 15) << 2;
      sKP[(d + 0) * 64 + j] = kreg[rep].x;
      sKP[(d + 1) * 64 + j] = kreg[rep].y;
      sKP[(d + 2) * 64 + j] = kreg[rep].z;
      sKP[(d + 3) * 64 + j] = kreg[rep].w;
      ((float4*)Vs)[u] = vreg[rep];
    }
    __syncthreads();

    // S[i][j] = sum_d Q[i][d] * K[j][d], outer-product over d
    float S[4][4] = {};
#pragma unroll 16
    for (int d = 0; d < 64; ++d) {
      const float4 av = *(const float4*)&QsT[d][ty * 4];
      const float4 bv = *(const float4*)&sKP[d * 64 + tx * 4];
      const float ar[4] = {av.x, av.y, av.z, av.w};
      const float br[4] = {bv.x, bv.y, bv.z, bv.w};
#pragma unroll
      for (int i = 0; i < 4; ++i)
#pragma unroll
        for (int j = 0; j < 4; ++j)
          S[i][j] = fmaf(ar[i], br[j], S[i][j]);
    }

    // online softmax per query row (rows spread over tx lanes, width-16 groups)
    float alpha[4];
#pragma unroll
    for (int i = 0; i < 4; ++i) {
#pragma unroll
      for (int j = 0; j < 4; ++j) S[i][j] *= ATTN_SCALE;
      float mx = fmaxf(fmaxf(S[i][0], S[i][1]), fmaxf(S[i][2], S[i][3]));
      mx = fmaxf(mx, __shfl_xor(mx, 1, 16));
      mx = fmaxf(mx, __shfl_xor(mx, 2, 16));
      mx = fmaxf(mx, __shfl_xor(mx, 4, 16));
      mx = fmaxf(mx, __shfl_xor(mx, 8, 16));
      const float mnew = fmaxf(m_i[i], mx);
      alpha[i] = __expf(m_i[i] - mnew);
      float s = 0.f;
#pragma unroll
      for (int j = 0; j < 4; ++j) {
        const float p = __expf(S[i][j] - mnew);
        S[i][j] = p;
        s += p;
      }
      s += __shfl_xor(s, 1, 16);
      s += __shfl_xor(s, 2, 16);
      s += __shfl_xor(s, 4, 16);
      s += __shfl_xor(s, 8, 16);
      l_i[i] = l_i[i] * alpha[i] + s;
      m_i[i] = mnew;
#pragma unroll
      for (int j = 0; j < 4; ++j) Oacc[i][j] *= alpha[i];
    }

    __syncthreads();  // all threads done reading KsT region of sKP
    // write P to LDS (stride-68 region of sKP)
#pragma unroll
    for (int i = 0; i < 4; ++i)
      *(float4*)&sKP[(ty * 4 + i) * 68 + tx * 4] =
          make_float4(S[i][0], S[i][1], S[i][2], S[i][3]);
    __syncthreads();

    // O[i][dv] += sum_j P[i][j] * V[j][dv]
#pragma unroll 16
    for (int j2 = 0; j2 < 64; ++j2) {
      const float4 vv = *(const float4*)&Vs[j2 * 64 + tx * 4];
      const float vr[4] = {vv.x, vv.y, vv.z, vv.w};
      float pr[4];
#pragma unroll
      for (int i = 0; i < 4; ++i) pr[i] = sKP[(ty * 4 + i) * 68 + j2];
#pragma unroll
      for (int i = 0; i < 4; ++i)
#pragma unroll
        for (int j = 0; j < 4; ++j)
          Oacc[i][j] = fmaf(pr[i], vr[j], Oacc[i][j]);
    }
  }

  // epilogue: normalize, write to [b*n][h*64+dv] so final GEMM reads row-major
  const int b = bh >> 4, h = bh & 15;
#pragma unroll
  for (int i = 0; i < 4; ++i) {
    const float inv = 1.0f / l_i[i];
    const int r = b * SEQ + qt * 64 + ty * 4 + i;
    const float4 val = make_float4(Oacc[i][0] * inv, Oacc[i][1] * inv,
                                   Oacc[i][2] * inv, Oacc[i][3] * inv);
    *(float4*)&Og[(size_t)r * DMODEL + h * DH + tx * 4] = val;
  }
}

extern "C" void kernel_launch(void* const* d_in, const int* in_sizes, int n_in,
                              void* d_out, int out_size, void* d_ws,
                              size_t ws_size, hipStream_t stream) {
  const float* patch = (const float*)d_in[0];
  const float* pixel = (const float*)d_in[1];
  const float* Wq = (const float*)d_in[2];
  const float* Wk = (const float*)d_in[3];
  const float* Wv = (const float*)d_in[4];
  const float* Wo = (const float*)d_in[5];
  const float* bo = (const float*)d_in[6];
  float* out = (float*)d_out;

  const size_t elems = (size_t)BB * SEQ * DMODEL;  // 4,194,304 floats
  float* qws = (float*)d_ws;         // [b][h][seq][dh]
  float* kws = qws + elems;          // [b][h][seq][dh]
  float* vws = kws + elems;          // [b][h][seq][dh]
  float* aws = vws + elems;          // [b*n][h*dh]

  const dim3 gg(DMODEL / 64, (BB * SEQ) / 64);  // (16, 64)
  gemm_tile<0><<<gg, 256, 0, stream>>>(patch, Wq, nullptr, qws, BB * SEQ, DMODEL, DMODEL);
  gemm_tile<0><<<gg, 256, 0, stream>>>(pixel, Wk, nullptr, kws, BB * SEQ, DMODEL, DMODEL);
  gemm_tile<0><<<gg, 256, 0, stream>>>(pixel, Wv, nullptr, vws, BB * SEQ, DMODEL, DMODEL);
  flash_attn<<<dim3(SEQ / 64, BB * HEADS), 256, 0, stream>>>(qws, kws, vws, aws);
  gemm_tile<1><<<gg, 256, 0, stream>>>(aws, Wo, bo, out, BB * SEQ, DMODEL, DMODEL);
}

// Round 2
// 448.119 us; speedup vs baseline: 2.8031x; 2.8031x over previous
//
#include <hip/hip_runtime.h>

#define SEQ 2048
#define DMODEL 1024
#define HEADS 16
#define DH 64
#define ATTN_SCALE 0.125f

typedef __attribute__((ext_vector_type(8))) short short8;
typedef __attribute__((ext_vector_type(4))) float f32x4;

__device__ __forceinline__ ushort f2bf(float x) {
  union { float f; unsigned u; } v; v.f = x;
  unsigned r = (v.u + 0x7fffu + ((v.u >> 16) & 1u)) >> 16;
  return (ushort)r;
}

// ---------------------------------------------------------------------------
// flat fp32 -> bf16 cast (4 elems/thread)
// ---------------------------------------------------------------------------
__global__ __launch_bounds__(256) void cast_bf16(const float4* __restrict__ in,
                                                 ushort4* __restrict__ out, int n4) {
  int i = blockIdx.x * 256 + threadIdx.x;
  if (i < n4) {
    float4 f = in[i];
    out[i] = make_ushort4(f2bf(f.x), f2bf(f.y), f2bf(f.z), f2bf(f.w));
  }
}

// ---------------------------------------------------------------------------
// W [K][N] fp32 -> Wt [N][K] bf16 (32x32 LDS tile transpose), block (32,8)
// ---------------------------------------------------------------------------
__global__ __launch_bounds__(256) void transpose_cast(const float* __restrict__ in,
                                                      ushort* __restrict__ out) {
  __shared__ float tile[32][33];
  const int tx = threadIdx.x, ty = threadIdx.y;
  const int n0 = blockIdx.x * 32, k0 = blockIdx.y * 32;
#pragma unroll
  for (int i = 0; i < 4; ++i)
    tile[ty + i * 8][tx] = in[(size_t)(k0 + ty + i * 8) * DMODEL + n0 + tx];
  __syncthreads();
#pragma unroll
  for (int i = 0; i < 4; ++i)
    out[(size_t)(n0 + ty + i * 8) * DMODEL + k0 + tx] = f2bf(tile[tx][ty + i * 8]);
}

// ---------------------------------------------------------------------------
// bf16 MFMA GEMM: C = A[4096,1024] @ Bt[1024,1024]^T  (Bt is [N][K] bf16)
// 128x128 tile, BK=64, 256 thr = 4 waves (2x2), each wave 64x64 via 4x4 MFMAs
// of 16x16x32. LDS stride 72 (pad 8) -> conflict-floor frag reads.
// MODE 0: bf16 scatter to [bh][seq][dh]   (Q, K)
// MODE 1: bf16 scatter to [bh][dh][seq]   (V, ushort4-packed over 4 rows)
// MODE 2: fp32 row-major + bias           (final out-projection)
// ---------------------------------------------------------------------------
template <int MODE>
__global__ __launch_bounds__(256) void mfma_gemm(const ushort* __restrict__ A,
                                                 const ushort* __restrict__ Bt,
                                                 const float* __restrict__ bias,
                                                 void* __restrict__ Cout) {
  __shared__ ushort As[128 * 72];
  __shared__ ushort Bs[128 * 72];
  const int t = threadIdx.x;
  const int w = t >> 6, lane = t & 63, ln = lane & 15, q = lane >> 4;
  const int wm = w & 1, wn = w >> 1;
  const int row0 = blockIdx.y * 128, col0 = blockIdx.x * 128;

  f32x4 acc[4][4];
#pragma unroll
  for (int i = 0; i < 4; ++i)
#pragma unroll
    for (int j = 0; j < 4; ++j) acc[i][j] = (f32x4){0.f, 0.f, 0.f, 0.f};

  for (int k0 = 0; k0 < DMODEL; k0 += 64) {
    uint4 ar[4], br[4];
#pragma unroll
    for (int rep = 0; rep < 4; ++rep) {
      const int u = t + rep * 256;
      const int r = u >> 3, ck = (u & 7) * 8;
      ar[rep] = *(const uint4*)&A[(size_t)(row0 + r) * DMODEL + k0 + ck];
      br[rep] = *(const uint4*)&Bt[(size_t)(col0 + r) * DMODEL + k0 + ck];
    }
    __syncthreads();
#pragma unroll
    for (int rep = 0; rep < 4; ++rep) {
      const int u = t + rep * 256;
      const int r = u >> 3, ck = (u & 7) * 8;
      *(uint4*)&As[r * 72 + ck] = ar[rep];
      *(uint4*)&Bs[r * 72 + ck] = br[rep];
    }
    __syncthreads();
#pragma unroll
    for (int ks = 0; ks < 2; ++ks) {
      short8 af[4], bf[4];
#pragma unroll
      for (int rt = 0; rt < 4; ++rt)
        af[rt] = *(const short8*)&As[(wm * 64 + rt * 16 + ln) * 72 + ks * 32 + q * 8];
#pragma unroll
      for (int ct = 0; ct < 4; ++ct)
        bf[ct] = *(const short8*)&Bs[(wn * 64 + ct * 16 + ln) * 72 + ks * 32 + q * 8];
#pragma unroll
      for (int rt = 0; rt < 4; ++rt)
#pragma unroll
        for (int ct = 0; ct < 4; ++ct)
          acc[rt][ct] = __builtin_amdgcn_mfma_f32_16x16x32_bf16(af[rt], bf[ct],
                                                                acc[rt][ct], 0, 0, 0);
    }
  }

  if (MODE == 0) {
    ushort* dst = (ushort*)Cout;
#pragma unroll
    for (int rt = 0; rt < 4; ++rt)
#pragma unroll
      for (int ct = 0; ct < 4; ++ct) {
        const int c = col0 + wn * 64 + ct * 16 + ln;
        const int h = c >> 6, d = c & 63;
#pragma unroll
        for (int reg = 0; reg < 4; ++reg) {
          const int r = row0 + wm * 64 + rt * 16 + q * 4 + reg;
          const int b = r >> 11, s = r & (SEQ - 1);
          dst[((size_t)(b * HEADS + h) * SEQ + s) * DH + d] = f2bf(acc[rt][ct][reg]);
        }
      }
  } else if (MODE == 1) {
    ushort* dst = (ushort*)Cout;
#pragma unroll
    for (int rt = 0; rt < 4; ++rt)
#pragma unroll
      for (int ct = 0; ct < 4; ++ct) {
        const int c = col0 + wn * 64 + ct * 16 + ln;
        const int h = c >> 6, d = c & 63;
        const int r0 = row0 + wm * 64 + rt * 16 + q * 4;
        const int b = r0 >> 11, s0 = r0 & (SEQ - 1);
        ushort4 u4 = make_ushort4(f2bf(acc[rt][ct][0]), f2bf(acc[rt][ct][1]),
                                  f2bf(acc[rt][ct][2]), f2bf(acc[rt][ct][3]));
        *(ushort4*)&dst[((size_t)(b * HEADS + h) * DH + d) * SEQ + s0] = u4;
      }
  } else {
    float* dst = (float*)Cout;
#pragma unroll
    for (int rt = 0; rt < 4; ++rt)
#pragma unroll
      for (int ct = 0; ct < 4; ++ct) {
        const int c = col0 + wn * 64 + ct * 16 + ln;
        const float bi = bias[c];
#pragma unroll
        for (int reg = 0; reg < 4; ++reg) {
          const int r = row0 + wm * 64 + rt * 16 + q * 4 + reg;
          dst[(size_t)r * DMODEL + c] = acc[rt][ct][reg] + bi;
        }
      }
  }
}

// ---------------------------------------------------------------------------
// bf16 MFMA flash attention. Block = (bh, 128-row Q tile), 256 thr = 4 waves,
// each wave owns 32 Q rows (2x 16). K-tile = 64. Online softmax per row.
// Q [bh][seq][64] bf16; K [bh][seq][64] bf16; V [bh][64][seq] bf16 (pre-T).
// P round-trips through the retired Q LDS region (wave-private rows).
// ---------------------------------------------------------------------------
__global__ __launch_bounds__(256) void flash_mfma(const ushort* __restrict__ Qg,
                                                  const ushort* __restrict__ Kg,
                                                  const ushort* __restrict__ Vg,
                                                  ushort* __restrict__ Og) {
  __shared__ ushort Qs[128 * 72];  // Q tile, then P tile (wave-private rows)
  __shared__ ushort Ks[64 * 72];
  __shared__ ushort Vts[64 * 72];

  const int t = threadIdx.x;
  const int w = t >> 6, lane = t & 63, ln = lane & 15, q = lane >> 4;
  const int qt = blockIdx.x;   // 0..15
  const int bh = blockIdx.y;   // 0..31

  const ushort* qg = Qg + (size_t)bh * SEQ * DH;
  const ushort* kg = Kg + (size_t)bh * SEQ * DH;
  const ushort* vg = Vg + (size_t)bh * DH * SEQ;

  // stage Q tile [128][64] -> LDS stride 72
#pragma unroll
  for (int rep = 0; rep < 4; ++rep) {
    const int u = t + rep * 256;
    const int r = u >> 3, ck = (u & 7) * 8;
    *(uint4*)&Qs[r * 72 + ck] = *(const uint4*)&qg[(size_t)(qt * 128 + r) * DH + ck];
  }
  __syncthreads();

  // A-fragments of Q, register-resident for the whole kernel
  short8 qf[2][2];
#pragma unroll
  for (int rt = 0; rt < 2; ++rt)
#pragma unroll
    for (int ks = 0; ks < 2; ++ks)
      qf[rt][ks] = *(const short8*)&Qs[(w * 32 + rt * 16 + ln) * 72 + ks * 32 + q * 8];

  float m_i[2][4], l_i[2][4];
  f32x4 acc_o[2][4];
#pragma unroll
  for (int rt = 0; rt < 2; ++rt)
#pragma unroll
    for (int reg = 0; reg < 4; ++reg) { m_i[rt][reg] = -1e30f; l_i[rt][reg] = 0.f; }
#pragma unroll
  for (int rt = 0; rt < 2; ++rt)
#pragma unroll
    for (int nt = 0; nt < 4; ++nt) acc_o[rt][nt] = (f32x4){0.f, 0.f, 0.f, 0.f};

  for (int kt = 0; kt < SEQ / 64; ++kt) {
    __syncthreads();  // all waves done reading Ks/Vts of previous iter
#pragma unroll
    for (int rep = 0; rep < 2; ++rep) {
      const int u = t + rep * 256;
      const int r = u >> 3, ck = (u & 7) * 8;
      *(uint4*)&Ks[r * 72 + ck] = *(const uint4*)&kg[(size_t)(kt * 64 + r) * DH + ck];
      *(uint4*)&Vts[r * 72 + ck] = *(const uint4*)&vg[(size_t)r * SEQ + kt * 64 + ck];
    }
    __syncthreads();

    // S = Q @ K^T  (per wave: 32 x 64)
    f32x4 accs[2][4];
#pragma unroll
    for (int rt = 0; rt < 2; ++rt)
#pragma unroll
      for (int ct = 0; ct < 4; ++ct) accs[rt][ct] = (f32x4){0.f, 0.f, 0.f, 0.f};
#pragma unroll
    for (int ks = 0; ks < 2; ++ks) {
      short8 bfr[4];
#pragma unroll
      for (int ct = 0; ct < 4; ++ct)
        bfr[ct] = *(const short8*)&Ks[(ct * 16 + ln) * 72 + ks * 32 + q * 8];
#pragma unroll
      for (int rt = 0; rt < 2; ++rt)
#pragma unroll
        for (int ct = 0; ct < 4; ++ct)
          accs[rt][ct] = __builtin_amdgcn_mfma_f32_16x16x32_bf16(qf[rt][ks], bfr[ct],
                                                                 accs[rt][ct], 0, 0, 0);
    }

    // online softmax per row (row = rt,reg; cols spread over quad's 16 lanes x 4 ct)
#pragma unroll
    for (int rt = 0; rt < 2; ++rt)
#pragma unroll
      for (int reg = 0; reg < 4; ++reg) {
        float mx = -1e30f;
#pragma unroll
        for (int ct = 0; ct < 4; ++ct) mx = fmaxf(mx, accs[rt][ct][reg]);
        mx = fmaxf(mx, __shfl_xor(mx, 1, 16));
        mx = fmaxf(mx, __shfl_xor(mx, 2, 16));
        mx = fmaxf(mx, __shfl_xor(mx, 4, 16));
        mx = fmaxf(mx, __shfl_xor(mx, 8, 16));
        mx *= ATTN_SCALE;
        const float mnew = fmaxf(m_i[rt][reg], mx);
        const float alpha = __expf(m_i[rt][reg] - mnew);
        float sum = 0.f;
#pragma unroll
        for (int ct = 0; ct < 4; ++ct) {
          const float p = __expf(accs[rt][ct][reg] * ATTN_SCALE - mnew);
          accs[rt][ct][reg] = p;
          sum += p;
        }
        sum += __shfl_xor(sum, 1, 16);
        sum += __shfl_xor(sum, 2, 16);
        sum += __shfl_xor(sum, 4, 16);
        sum += __shfl_xor(sum, 8, 16);
        l_i[rt][reg] = l_i[rt][reg] * alpha + sum;
        m_i[rt][reg] = mnew;
#pragma unroll
        for (int nt = 0; nt < 4; ++nt) acc_o[rt][nt][reg] *= alpha;
      }

    // P (C/D layout) -> bf16 -> wave-private LDS rows (A-operand layout source)
#pragma unroll
    for (int rt = 0; rt < 2; ++rt)
#pragma unroll
      for (int ct = 0; ct < 4; ++ct)
#pragma unroll
        for (int reg = 0; reg < 4; ++reg)
          Qs[(w * 32 + rt * 16 + q * 4 + reg) * 72 + ct * 16 + ln] =
              f2bf(accs[rt][ct][reg]);

    // O += P @ V
#pragma unroll
    for (int ks2 = 0; ks2 < 2; ++ks2) {
      short8 pa[2];
#pragma unroll
      for (int rt = 0; rt < 2; ++rt)
        pa[rt] = *(const short8*)&Qs[(w * 32 + rt * 16 + ln) * 72 + ks2 * 32 + q * 8];
#pragma unroll
      for (int nt = 0; nt < 4; ++nt) {
        const short8 bv = *(const short8*)&Vts[(nt * 16 + ln) * 72 + ks2 * 32 + q * 8];
#pragma unroll
        for (int rt = 0; rt < 2; ++rt)
          acc_o[rt][nt] = __builtin_amdgcn_mfma_f32_16x16x32_bf16(pa[rt], bv,
                                                                  acc_o[rt][nt], 0, 0, 0);
      }
    }
  }

  // epilogue: normalize, write bf16 to aws [b*2048+s][h*64+d]
  const int b = bh >> 4, h = bh & 15;
#pragma unroll
  for (int rt = 0; rt < 2; ++rt)
#pragma unroll
    for (int reg = 0; reg < 4; ++reg) {
      const float inv = 1.0f / l_i[rt][reg];
      const int s = qt * 128 + w * 32 + rt * 16 + q * 4 + reg;
#pragma unroll
      for (int nt = 0; nt < 4; ++nt)
        Og[(size_t)(b * SEQ + s) * DMODEL + h * DH + nt * 16 + ln] =
            f2bf(acc_o[rt][nt][reg] * inv);
    }
}

extern "C" void kernel_launch(void* const* d_in, const int* in_sizes, int n_in,
                              void* d_out, int out_size, void* d_ws,
                              size_t ws_size, hipStream_t stream) {
  const float* patch = (const float*)d_in[0];
  const float* pixel = (const float*)d_in[1];
  const float* Wq = (const float*)d_in[2];
  const float* Wk = (const float*)d_in[3];
  const float* Wv = (const float*)d_in[4];
  const float* Wo = (const float*)d_in[5];
  const float* bo = (const float*)d_in[6];
  float* out = (float*)d_out;

  const size_t E = (size_t)2 * SEQ * DMODEL;  // 4,194,304
  const size_t W = (size_t)DMODEL * DMODEL;   // 1,048,576
  ushort* pb  = (ushort*)d_ws;      // patch bf16
  ushort* xb  = pb + E;             // pixel bf16
  ushort* wqt = xb + E;             // Wq^T bf16 [N][K]
  ushort* wkt = wqt + W;
  ushort* wvt = wkt + W;
  ushort* wot = wvt + W;
  ushort* qws = wot + W;            // [bh][seq][64]
  ushort* kws = qws + E;            // [bh][seq][64]
  ushort* vws = kws + E;            // [bh][64][seq]
  ushort* aws = vws + E;            // [4096][1024]

  cast_bf16<<<dim3((E / 4 + 255) / 256), 256, 0, stream>>>((const float4*)patch,
                                                           (ushort4*)pb, E / 4);
  cast_bf16<<<dim3((E / 4 + 255) / 256), 256, 0, stream>>>((const float4*)pixel,
                                                           (ushort4*)xb, E / 4);
  const dim3 tb(32, 8);
  transpose_cast<<<dim3(32, 32), tb, 0, stream>>>(Wq, wqt);
  transpose_cast<<<dim3(32, 32), tb, 0, stream>>>(Wk, wkt);
  transpose_cast<<<dim3(32, 32), tb, 0, stream>>>(Wv, wvt);
  transpose_cast<<<dim3(32, 32), tb, 0, stream>>>(Wo, wot);

  const dim3 gg(DMODEL / 128, 2 * SEQ / 128);  // (8, 32)
  mfma_gemm<0><<<gg, 256, 0, stream>>>(pb, wqt, nullptr, qws);
  mfma_gemm<0><<<gg, 256, 0, stream>>>(xb, wkt, nullptr, kws);
  mfma_gemm<1><<<gg, 256, 0, stream>>>(xb, wvt, nullptr, vws);

  flash_mfma<<<dim3(SEQ / 128, 2 * HEADS), 256, 0, stream>>>(qws, kws, vws, aws);

  mfma_gemm<2><<<gg, 256, 0, stream>>>(aws, wot, bo, out);
}

// Round 3
// 423.261 us; speedup vs baseline: 2.9677x; 1.0587x over previous
//
#include <hip/hip_runtime.h>

#define SEQ 2048
#define DMODEL 1024
#define HEADS 16
#define DH 64
// fold 1/sqrt(64) * log2(e) into Wq so S arrives in exp2 domain
#define QSCALE 0.180336880f

typedef __attribute__((ext_vector_type(8))) short short8;
typedef __attribute__((ext_vector_type(4))) float f32x4;

__device__ __forceinline__ ushort f2bf(float x) {
  union { float f; unsigned u; } v; v.f = x;
  return (ushort)((v.u + 0x7fffu + ((v.u >> 16) & 1u)) >> 16);
}

// ---------------------------------------------------------------------------
// fp32 -> bf16 cast; z picks (patch, pixel)
// ---------------------------------------------------------------------------
__global__ __launch_bounds__(256) void cast_bf16(const float4* __restrict__ in0,
                                                 const float4* __restrict__ in1,
                                                 ushort4* __restrict__ out0,
                                                 ushort4* __restrict__ out1, int n4) {
  const float4* in = blockIdx.z ? in1 : in0;
  ushort4* out = blockIdx.z ? out1 : out0;
  int i = blockIdx.x * 256 + threadIdx.x;
  if (i < n4) {
    float4 f = in[i];
    out[i] = make_ushort4(f2bf(f.x), f2bf(f.y), f2bf(f.z), f2bf(f.w));
  }
}

// ---------------------------------------------------------------------------
// W [K][N] fp32 -> Wt [N][K] bf16 (*scale for z==0), z picks Wq/Wk/Wv/Wo
// ---------------------------------------------------------------------------
__global__ __launch_bounds__(256) void transpose_cast(
    const float* __restrict__ W0, const float* __restrict__ W1,
    const float* __restrict__ W2, const float* __restrict__ W3,
    ushort* __restrict__ O0, ushort* __restrict__ O1,
    ushort* __restrict__ O2, ushort* __restrict__ O3) {
  __shared__ float tile[32][33];
  const int z = blockIdx.z;
  const float* in = z == 0 ? W0 : z == 1 ? W1 : z == 2 ? W2 : W3;
  ushort* out = z == 0 ? O0 : z == 1 ? O1 : z == 2 ? O2 : O3;
  const float scale = z == 0 ? QSCALE : 1.0f;
  const int tx = threadIdx.x, ty = threadIdx.y;
  const int n0 = blockIdx.x * 32, k0 = blockIdx.y * 32;
#pragma unroll
  for (int i = 0; i < 4; ++i)
    tile[ty + i * 8][tx] = in[(size_t)(k0 + ty + i * 8) * DMODEL + n0 + tx];
  __syncthreads();
#pragma unroll
  for (int i = 0; i < 4; ++i)
    out[(size_t)(n0 + ty + i * 8) * DMODEL + k0 + tx] =
        f2bf(tile[tx][ty + i * 8] * scale);
}

// ---------------------------------------------------------------------------
// Fused Q/K/V projection GEMM. z=0: patch@WqT -> qws [bh][s][64] (bf16)
// z=1: pixel@WkT -> kws [bh][s][64]   z=2: pixel@WvT -> vws [bh][64][s]
// 128x128 tile, BK=64, 4 waves 2x2, 16x16x32 MFMA. 768 blocks = 3/CU.
// ---------------------------------------------------------------------------
__global__ __launch_bounds__(256) void mfma_gemm_qkv(
    const ushort* __restrict__ pb, const ushort* __restrict__ xb,
    const ushort* __restrict__ wqt, const ushort* __restrict__ wkt,
    const ushort* __restrict__ wvt, ushort* __restrict__ qws,
    ushort* __restrict__ kws, ushort* __restrict__ vws) {
  __shared__ ushort As[128 * 72];
  __shared__ ushort Bs[128 * 72];
  const int z = blockIdx.z;
  const ushort* A = (z == 0) ? pb : xb;
  const ushort* Bt = (z == 0) ? wqt : (z == 1) ? wkt : wvt;

  const int t = threadIdx.x;
  const int w = t >> 6, lane = t & 63, ln = lane & 15, q = lane >> 4;
  const int wm = w & 1, wn = w >> 1;
  const int row0 = blockIdx.y * 128, col0 = blockIdx.x * 128;

  f32x4 acc[4][4];
#pragma unroll
  for (int i = 0; i < 4; ++i)
#pragma unroll
    for (int j = 0; j < 4; ++j) acc[i][j] = (f32x4){0.f, 0.f, 0.f, 0.f};

  for (int k0 = 0; k0 < DMODEL; k0 += 64) {
    uint4 ar[4], br[4];
#pragma unroll
    for (int rep = 0; rep < 4; ++rep) {
      const int u = t + rep * 256;
      const int r = u >> 3, ck = (u & 7) * 8;
      ar[rep] = *(const uint4*)&A[(size_t)(row0 + r) * DMODEL + k0 + ck];
      br[rep] = *(const uint4*)&Bt[(size_t)(col0 + r) * DMODEL + k0 + ck];
    }
    __syncthreads();
#pragma unroll
    for (int rep = 0; rep < 4; ++rep) {
      const int u = t + rep * 256;
      const int r = u >> 3, ck = (u & 7) * 8;
      *(uint4*)&As[r * 72 + ck] = ar[rep];
      *(uint4*)&Bs[r * 72 + ck] = br[rep];
    }
    __syncthreads();
#pragma unroll
    for (int ks = 0; ks < 2; ++ks) {
      short8 af[4], bf[4];
#pragma unroll
      for (int rt = 0; rt < 4; ++rt)
        af[rt] = *(const short8*)&As[(wm * 64 + rt * 16 + ln) * 72 + ks * 32 + q * 8];
#pragma unroll
      for (int ct = 0; ct < 4; ++ct)
        bf[ct] = *(const short8*)&Bs[(wn * 64 + ct * 16 + ln) * 72 + ks * 32 + q * 8];
#pragma unroll
      for (int rt = 0; rt < 4; ++rt)
#pragma unroll
        for (int ct = 0; ct < 4; ++ct)
          acc[rt][ct] = __builtin_amdgcn_mfma_f32_16x16x32_bf16(af[rt], bf[ct],
                                                                acc[rt][ct], 0, 0, 0);
    }
  }

  if (z < 2) {
    ushort* dst = z == 0 ? qws : kws;
#pragma unroll
    for (int rt = 0; rt < 4; ++rt)
#pragma unroll
      for (int ct = 0; ct < 4; ++ct) {
        const int c = col0 + wn * 64 + ct * 16 + ln;
        const int h = c >> 6, d = c & 63;
#pragma unroll
        for (int reg = 0; reg < 4; ++reg) {
          const int r = row0 + wm * 64 + rt * 16 + q * 4 + reg;
          const int b = r >> 11, s = r & (SEQ - 1);
          dst[((size_t)(b * HEADS + h) * SEQ + s) * DH + d] = f2bf(acc[rt][ct][reg]);
        }
      }
  } else {
#pragma unroll
    for (int rt = 0; rt < 4; ++rt)
#pragma unroll
      for (int ct = 0; ct < 4; ++ct) {
        const int c = col0 + wn * 64 + ct * 16 + ln;
        const int h = c >> 6, d = c & 63;
        const int r0 = row0 + wm * 64 + rt * 16 + q * 4;
        const int b = r0 >> 11, s0 = r0 & (SEQ - 1);
        ushort4 u4 = make_ushort4(f2bf(acc[rt][ct][0]), f2bf(acc[rt][ct][1]),
                                  f2bf(acc[rt][ct][2]), f2bf(acc[rt][ct][3]));
        *(ushort4*)&vws[((size_t)(b * HEADS + h) * DH + d) * SEQ + s0] = u4;
      }
  }
}

// ---------------------------------------------------------------------------
// Barrier-free bf16 MFMA flash attention, max-free exp2 softmax.
// Q pre-scaled by QSCALE. K/V^T B-fragments loaded DIRECTLY from global
// (16B/lane, L1-served). LDS only: Q stage -> qf frags, then wave-private
// P round-trip. One __syncthreads total.
// ---------------------------------------------------------------------------
__global__ __launch_bounds__(256) void flash_mfma(const ushort* __restrict__ Qg,
                                                  const ushort* __restrict__ Kg,
                                                  const ushort* __restrict__ Vg,
                                                  ushort* __restrict__ Og) {
  __shared__ ushort Qs[128 * 72];

  const int t = threadIdx.x;
  const int w = t >> 6, lane = t & 63, ln = lane & 15, q = lane >> 4;
  const int qt = blockIdx.x;   // 0..15
  const int bh = blockIdx.y;   // 0..31

  const ushort* qg = Qg + (size_t)bh * SEQ * DH;
  const ushort* kg = Kg + (size_t)bh * SEQ * DH;
  const ushort* vg = Vg + (size_t)bh * DH * SEQ;

  // stage Q tile [128][64] -> LDS stride 72
#pragma unroll
  for (int rep = 0; rep < 4; ++rep) {
    const int u = t + rep * 256;
    const int r = u >> 3, ck = (u & 7) * 8;
    *(uint4*)&Qs[r * 72 + ck] = *(const uint4*)&qg[(size_t)(qt * 128 + r) * DH + ck];
  }
  __syncthreads();

  short8 qf[2][2];
#pragma unroll
  for (int rt = 0; rt < 2; ++rt)
#pragma unroll
    for (int ks = 0; ks < 2; ++ks)
      qf[rt][ks] = *(const short8*)&Qs[(w * 32 + rt * 16 + ln) * 72 + ks * 32 + q * 8];
  // After this point Qs rows w*32..w*32+31 are wave-private (P buffer).

  float l_i[2][4];
  f32x4 acc_o[2][4];
#pragma unroll
  for (int rt = 0; rt < 2; ++rt)
#pragma unroll
    for (int reg = 0; reg < 4; ++reg) l_i[rt][reg] = 0.f;
#pragma unroll
  for (int rt = 0; rt < 2; ++rt)
#pragma unroll
    for (int nt = 0; nt < 4; ++nt) acc_o[rt][nt] = (f32x4){0.f, 0.f, 0.f, 0.f};

  for (int kt = 0; kt < SEQ / 64; ++kt) {
    // S = Q @ K^T (per wave 32x64); K B-frags straight from global
    f32x4 accs[2][4];
#pragma unroll
    for (int rt = 0; rt < 2; ++rt)
#pragma unroll
      for (int ct = 0; ct < 4; ++ct) accs[rt][ct] = (f32x4){0.f, 0.f, 0.f, 0.f};
#pragma unroll
    for (int ks = 0; ks < 2; ++ks) {
      short8 bfr[4];
#pragma unroll
      for (int ct = 0; ct < 4; ++ct)
        bfr[ct] = *(const short8*)&kg[(size_t)(kt * 64 + ct * 16 + ln) * DH + ks * 32 + q * 8];
#pragma unroll
      for (int rt = 0; rt < 2; ++rt)
#pragma unroll
        for (int ct = 0; ct < 4; ++ct)
          accs[rt][ct] = __builtin_amdgcn_mfma_f32_16x16x32_bf16(qf[rt][ks], bfr[ct],
                                                                 accs[rt][ct], 0, 0, 0);
    }

    // max-free softmax: p = 2^s (Q pre-scaled), lane-partial l, no shuffles
#pragma unroll
    for (int rt = 0; rt < 2; ++rt)
#pragma unroll
      for (int ct = 0; ct < 4; ++ct) {
#pragma unroll
        for (int reg = 0; reg < 4; ++reg) {
          const float p = __builtin_amdgcn_exp2f(accs[rt][ct][reg]);
          accs[rt][ct][reg] = p;
          l_i[rt][reg] += p;
        }
        // P (C/D layout) -> bf16 -> wave-private LDS rows
#pragma unroll
        for (int reg = 0; reg < 4; ++reg)
          Qs[(w * 32 + rt * 16 + q * 4 + reg) * 72 + ct * 16 + ln] =
              f2bf(accs[rt][ct][reg]);
      }

    // O += P @ V ; V^T B-frags straight from global
#pragma unroll
    for (int ks2 = 0; ks2 < 2; ++ks2) {
      short8 pa[2];
#pragma unroll
      for (int rt = 0; rt < 2; ++rt)
        pa[rt] = *(const short8*)&Qs[(w * 32 + rt * 16 + ln) * 72 + ks2 * 32 + q * 8];
#pragma unroll
      for (int nt = 0; nt < 4; ++nt) {
        const short8 bv = *(const short8*)&vg[(size_t)(nt * 16 + ln) * SEQ + kt * 64 + ks2 * 32 + q * 8];
#pragma unroll
        for (int rt = 0; rt < 2; ++rt)
          acc_o[rt][nt] = __builtin_amdgcn_mfma_f32_16x16x32_bf16(pa[rt], bv,
                                                                  acc_o[rt][nt], 0, 0, 0);
      }
    }
  }

  // epilogue: reduce l across the 16 lanes of each row, normalize, store
  const int b = bh >> 4, h = bh & 15;
#pragma unroll
  for (int rt = 0; rt < 2; ++rt)
#pragma unroll
    for (int reg = 0; reg < 4; ++reg) {
      float l = l_i[rt][reg];
      l += __shfl_xor(l, 1, 16);
      l += __shfl_xor(l, 2, 16);
      l += __shfl_xor(l, 4, 16);
      l += __shfl_xor(l, 8, 16);
      const float inv = 1.0f / l;
      const int s = qt * 128 + w * 32 + rt * 16 + q * 4 + reg;
#pragma unroll
      for (int nt = 0; nt < 4; ++nt)
        Og[(size_t)(b * SEQ + s) * DMODEL + h * DH + nt * 16 + ln] =
            f2bf(acc_o[rt][nt][reg] * inv);
    }
}

// ---------------------------------------------------------------------------
// Output projection: out = aws[4096,1024] @ WoT^T + bo (fp32). 64x128 tile,
// BK=64, 4 waves 2x2 (each 32x64). 512 blocks = 2/CU.
// ---------------------------------------------------------------------------
__global__ __launch_bounds__(256) void mfma_gemm_out(const ushort* __restrict__ A,
                                                     const ushort* __restrict__ Bt,
                                                     const float* __restrict__ bias,
                                                     float* __restrict__ dst) {
  __shared__ ushort As[64 * 72];
  __shared__ ushort Bs[128 * 72];
  const int t = threadIdx.x;
  const int w = t >> 6, lane = t & 63, ln = lane & 15, q = lane >> 4;
  const int wm = w & 1, wn = w >> 1;
  const int row0 = blockIdx.y * 64, col0 = blockIdx.x * 128;

  f32x4 acc[2][4];
#pragma unroll
  for (int i = 0; i < 2; ++i)
#pragma unroll
    for (int j = 0; j < 4; ++j) acc[i][j] = (f32x4){0.f, 0.f, 0.f, 0.f};

  for (int k0 = 0; k0 < DMODEL; k0 += 64) {
    uint4 ar[2], br[4];
#pragma unroll
    for (int rep = 0; rep < 2; ++rep) {
      const int u = t + rep * 256;
      const int r = u >> 3, ck = (u & 7) * 8;
      ar[rep] = *(const uint4*)&A[(size_t)(row0 + r) * DMODEL + k0 + ck];
    }
#pragma unroll
    for (int rep = 0; rep < 4; ++rep) {
      const int u = t + rep * 256;
      const int r = u >> 3, ck = (u & 7) * 8;
      br[rep] = *(const uint4*)&Bt[(size_t)(col0 + r) * DMODEL + k0 + ck];
    }
    __syncthreads();
#pragma unroll
    for (int rep = 0; rep < 2; ++rep) {
      const int u = t + rep * 256;
      *(uint4*)&As[(u >> 3) * 72 + (u & 7) * 8] = ar[rep];
    }
#pragma unroll
    for (int rep = 0; rep < 4; ++rep) {
      const int u = t + rep * 256;
      *(uint4*)&Bs[(u >> 3) * 72 + (u & 7) * 8] = br[rep];
    }
    __syncthreads();
#pragma unroll
    for (int ks = 0; ks < 2; ++ks) {
      short8 af[2], bf[4];
#pragma unroll
      for (int rt = 0; rt < 2; ++rt)
        af[rt] = *(const short8*)&As[(wm * 32 + rt * 16 + ln) * 72 + ks * 32 + q * 8];
#pragma unroll
      for (int ct = 0; ct < 4; ++ct)
        bf[ct] = *(const short8*)&Bs[(wn * 64 + ct * 16 + ln) * 72 + ks * 32 + q * 8];
#pragma unroll
      for (int rt = 0; rt < 2; ++rt)
#pragma unroll
        for (int ct = 0; ct < 4; ++ct)
          acc[rt][ct] = __builtin_amdgcn_mfma_f32_16x16x32_bf16(af[rt], bf[ct],
                                                                acc[rt][ct], 0, 0, 0);
    }
  }

#pragma unroll
  for (int rt = 0; rt < 2; ++rt)
#pragma unroll
    for (int ct = 0; ct < 4; ++ct) {
      const int c = col0 + wn * 64 + ct * 16 + ln;
      const float bi = bias[c];
#pragma unroll
      for (int reg = 0; reg < 4; ++reg) {
        const int r = row0 + wm * 32 + rt * 16 + q * 4 + reg;
        dst[(size_t)r * DMODEL + c] = acc[rt][ct][reg] + bi;
      }
    }
}

extern "C" void kernel_launch(void* const* d_in, const int* in_sizes, int n_in,
                              void* d_out, int out_size, void* d_ws,
                              size_t ws_size, hipStream_t stream) {
  const float* patch = (const float*)d_in[0];
  const float* pixel = (const float*)d_in[1];
  const float* Wq = (const float*)d_in[2];
  const float* Wk = (const float*)d_in[3];
  const float* Wv = (const float*)d_in[4];
  const float* Wo = (const float*)d_in[5];
  const float* bo = (const float*)d_in[6];
  float* out = (float*)d_out;

  const size_t E = (size_t)2 * SEQ * DMODEL;  // 4,194,304
  const size_t W = (size_t)DMODEL * DMODEL;   // 1,048,576
  ushort* pb  = (ushort*)d_ws;      // patch bf16
  ushort* xb  = pb + E;             // pixel bf16
  ushort* wqt = xb + E;             // Wq^T * QSCALE, bf16 [N][K]
  ushort* wkt = wqt + W;
  ushort* wvt = wkt + W;
  ushort* wot = wvt + W;
  ushort* qws = wot + W;            // [bh][seq][64]
  ushort* kws = qws + E;            // [bh][seq][64]
  ushort* vws = kws + E;            // [bh][64][seq]
  ushort* aws = vws + E;            // [4096][1024]

  cast_bf16<<<dim3(E / 4 / 256, 1, 2), 256, 0, stream>>>(
      (const float4*)patch, (const float4*)pixel, (ushort4*)pb, (ushort4*)xb, E / 4);
  transpose_cast<<<dim3(32, 32, 4), dim3(32, 8), 0, stream>>>(
      Wq, Wk, Wv, Wo, wqt, wkt, wvt, wot);
  mfma_gemm_qkv<<<dim3(8, 32, 3), 256, 0, stream>>>(pb, xb, wqt, wkt, wvt,
                                                    qws, kws, vws);
  flash_mfma<<<dim3(SEQ / 128, 2 * HEADS), 256, 0, stream>>>(qws, kws, vws, aws);
  mfma_gemm_out<<<dim3(8, 64), 256, 0, stream>>>(aws, wot, bo, out);
}

// Round 4
// 396.544 us; speedup vs baseline: 3.1677x; 1.0674x over previous
//
#include <hip/hip_runtime.h>

#define SEQ 2048
#define DMODEL 1024
#define HEADS 16
#define DH 64
// fold (1/sqrt(64)) * log2(e) into Wq so scores arrive in exp2 domain
#define QSCALE 0.180336880f

typedef __attribute__((ext_vector_type(8))) short short8;
typedef __attribute__((ext_vector_type(4))) float f32x4;

__device__ __forceinline__ ushort f2bf(float x) {
  union { float f; unsigned u; } v; v.f = x;
  return (ushort)((v.u + 0x7fffu + ((v.u >> 16) & 1u)) >> 16);
}

// async global->LDS, 16B per lane. LDS dest = wave-uniform base + lane*16.
__device__ __forceinline__ void gld16(const ushort* g, ushort* l) {
  __builtin_amdgcn_global_load_lds(
      (const __attribute__((address_space(1))) unsigned int*)g,
      (__attribute__((address_space(3))) unsigned int*)l, 16, 0, 0);
}

// ---------------------------------------------------------------------------
// fp32 -> bf16 cast; z picks (patch, pixel)
// ---------------------------------------------------------------------------
__global__ __launch_bounds__(256) void cast_bf16(const float4* __restrict__ in0,
                                                 const float4* __restrict__ in1,
                                                 ushort4* __restrict__ out0,
                                                 ushort4* __restrict__ out1, int n4) {
  const float4* in = blockIdx.z ? in1 : in0;
  ushort4* out = blockIdx.z ? out1 : out0;
  int i = blockIdx.x * 256 + threadIdx.x;
  if (i < n4) {
    float4 f = in[i];
    out[i] = make_ushort4(f2bf(f.x), f2bf(f.y), f2bf(f.z), f2bf(f.w));
  }
}

// ---------------------------------------------------------------------------
// W [K][N] fp32 -> Wt [N][K] bf16 (*QSCALE for z==0), z picks Wq/Wk/Wv/Wo
// ---------------------------------------------------------------------------
__global__ __launch_bounds__(256) void transpose_cast(
    const float* __restrict__ W0, const float* __restrict__ W1,
    const float* __restrict__ W2, const float* __restrict__ W3,
    ushort* __restrict__ O0, ushort* __restrict__ O1,
    ushort* __restrict__ O2, ushort* __restrict__ O3) {
  __shared__ float tile[32][33];
  const int z = blockIdx.z;
  const float* in = z == 0 ? W0 : z == 1 ? W1 : z == 2 ? W2 : W3;
  ushort* out = z == 0 ? O0 : z == 1 ? O1 : z == 2 ? O2 : O3;
  const float scale = z == 0 ? QSCALE : 1.0f;
  const int tx = threadIdx.x, ty = threadIdx.y;
  const int n0 = blockIdx.x * 32, k0 = blockIdx.y * 32;
#pragma unroll
  for (int i = 0; i < 4; ++i)
    tile[ty + i * 8][tx] = in[(size_t)(k0 + ty + i * 8) * DMODEL + n0 + tx];
  __syncthreads();
#pragma unroll
  for (int i = 0; i < 4; ++i)
    out[(size_t)(n0 + ty + i * 8) * DMODEL + k0 + tx] =
        f2bf(tile[tx][ty + i * 8] * scale);
}

// ---------------------------------------------------------------------------
// Fused Q/K/V projection GEMM, global_load_lds(16B) staging, XOR-swizzled on
// the GLOBAL side (LDS dest lane-contiguous). 128x128 tile, BK=64, 4 waves.
// z=0: patch@WqT -> qws [bh][s][64]; z=1: pixel@WkT -> kws; z=2 -> vws [bh][64][s]
// ---------------------------------------------------------------------------
__global__ __launch_bounds__(256) void mfma_gemm_qkv(
    const ushort* __restrict__ pb, const ushort* __restrict__ xb,
    const ushort* __restrict__ wqt, const ushort* __restrict__ wkt,
    const ushort* __restrict__ wvt, ushort* __restrict__ qws,
    ushort* __restrict__ kws, ushort* __restrict__ vws) {
  __shared__ __align__(16) ushort As[128 * 64];
  __shared__ __align__(16) ushort Bs[128 * 64];
  const int z = blockIdx.z;
  const ushort* A = (z == 0) ? pb : xb;
  const ushort* Bt = (z == 0) ? wqt : (z == 1) ? wkt : wvt;

  const int t = threadIdx.x;
  const int w = t >> 6, lane = t & 63, ln = lane & 15, q = lane >> 4;
  const int wm = w & 1, wn = w >> 1;
  const int row0 = blockIdx.y * 128, col0 = blockIdx.x * 128;
  const int sw = ln & 7;

  f32x4 acc[4][4];
#pragma unroll
  for (int i = 0; i < 4; ++i)
#pragma unroll
    for (int j = 0; j < 4; ++j) acc[i][j] = (f32x4){0.f, 0.f, 0.f, 0.f};

  for (int k0 = 0; k0 < DMODEL; k0 += 64) {
    __syncthreads();  // prior frag reads done
#pragma unroll
    for (int rep = 0; rep < 4; ++rep) {
      const int u0 = rep * 256 + w * 64;
      const int u = u0 + lane;
      const int r = u >> 3, gl = (u & 7) ^ (r & 7);
      gld16(&A[(size_t)(row0 + r) * DMODEL + k0 + gl * 8], &As[u0 * 8]);
      gld16(&Bt[(size_t)(col0 + r) * DMODEL + k0 + gl * 8], &Bs[u0 * 8]);
    }
    __syncthreads();  // vmcnt drain
#pragma unroll
    for (int ks = 0; ks < 2; ++ks) {
      short8 af[4], bf[4];
#pragma unroll
      for (int rt = 0; rt < 4; ++rt)
        af[rt] = *(const short8*)&As[(wm * 64 + rt * 16 + ln) * 64 +
                                     (((ks * 4 + q) ^ sw) * 8)];
#pragma unroll
      for (int ct = 0; ct < 4; ++ct)
        bf[ct] = *(const short8*)&Bs[(wn * 64 + ct * 16 + ln) * 64 +
                                     (((ks * 4 + q) ^ sw) * 8)];
#pragma unroll
      for (int rt = 0; rt < 4; ++rt)
#pragma unroll
        for (int ct = 0; ct < 4; ++ct)
          acc[rt][ct] = __builtin_amdgcn_mfma_f32_16x16x32_bf16(af[rt], bf[ct],
                                                                acc[rt][ct], 0, 0, 0);
    }
  }

  if (z < 2) {
    ushort* dst = z == 0 ? qws : kws;
#pragma unroll
    for (int rt = 0; rt < 4; ++rt)
#pragma unroll
      for (int ct = 0; ct < 4; ++ct) {
        const int c = col0 + wn * 64 + ct * 16 + ln;
        const int h = c >> 6, d = c & 63;
#pragma unroll
        for (int reg = 0; reg < 4; ++reg) {
          const int r = row0 + wm * 64 + rt * 16 + q * 4 + reg;
          const int b = r >> 11, s = r & (SEQ - 1);
          dst[((size_t)(b * HEADS + h) * SEQ + s) * DH + d] = f2bf(acc[rt][ct][reg]);
        }
      }
  } else {
#pragma unroll
    for (int rt = 0; rt < 4; ++rt)
#pragma unroll
      for (int ct = 0; ct < 4; ++ct) {
        const int c = col0 + wn * 64 + ct * 16 + ln;
        const int h = c >> 6, d = c & 63;
        const int r0 = row0 + wm * 64 + rt * 16 + q * 4;
        const int b = r0 >> 11, s0 = r0 & (SEQ - 1);
        ushort4 u4 = make_ushort4(f2bf(acc[rt][ct][0]), f2bf(acc[rt][ct][1]),
                                  f2bf(acc[rt][ct][2]), f2bf(acc[rt][ct][3]));
        *(ushort4*)&vws[((size_t)(b * HEADS + h) * DH + d) * SEQ + s0] = u4;
      }
  }
}

// ---------------------------------------------------------------------------
// Flash attention, K-split x2 with ADDITIVE partial merge (max-free exp2
// softmax => partials sum). Zero barriers. Q-tile 64 (wave-per-16-rows),
// K/V/Q fragments straight from global, P via wave-private LDS.
// Grid (32 qt, 32 bh, 2 seg) = 2048 blocks = 8 blocks/CU.
// ---------------------------------------------------------------------------
__global__ __launch_bounds__(256) void flash_mfma(const ushort* __restrict__ Qg,
                                                  const ushort* __restrict__ Kg,
                                                  const ushort* __restrict__ Vg,
                                                  float* __restrict__ PO,
                                                  float* __restrict__ Lb) {
  __shared__ __align__(16) ushort Ps[64 * 72];

  const int t = threadIdx.x;
  const int w = t >> 6, lane = t & 63, ln = lane & 15, q = lane >> 4;
  const int qt = blockIdx.x;   // 0..31
  const int bh = blockIdx.y;   // 0..31
  const int seg = blockIdx.z;  // 0..1

  const ushort* qg = Qg + (size_t)bh * SEQ * DH;
  const ushort* kg = Kg + (size_t)bh * SEQ * DH;
  const ushort* vg = Vg + (size_t)bh * DH * SEQ;

  // Q A-fragments straight from global (once)
  short8 qf[2];
#pragma unroll
  for (int ks = 0; ks < 2; ++ks)
    qf[ks] = *(const short8*)&qg[(size_t)(qt * 64 + w * 16 + ln) * DH + ks * 32 + q * 8];

  float l_i[4] = {0.f, 0.f, 0.f, 0.f};
  f32x4 acc_o[4];
#pragma unroll
  for (int nt = 0; nt < 4; ++nt) acc_o[nt] = (f32x4){0.f, 0.f, 0.f, 0.f};

  for (int kt = seg * 16; kt < seg * 16 + 16; ++kt) {
    // S = Q @ K^T (wave: 16x64)
    f32x4 accs[4];
#pragma unroll
    for (int ct = 0; ct < 4; ++ct) accs[ct] = (f32x4){0.f, 0.f, 0.f, 0.f};
#pragma unroll
    for (int ks = 0; ks < 2; ++ks) {
      short8 bfr[4];
#pragma unroll
      for (int ct = 0; ct < 4; ++ct)
        bfr[ct] = *(const short8*)&kg[(size_t)(kt * 64 + ct * 16 + ln) * DH +
                                      ks * 32 + q * 8];
#pragma unroll
      for (int ct = 0; ct < 4; ++ct)
        accs[ct] = __builtin_amdgcn_mfma_f32_16x16x32_bf16(qf[ks], bfr[ct],
                                                           accs[ct], 0, 0, 0);
    }

    // p = 2^s, lane-partial l, P -> wave-private LDS rows
#pragma unroll
    for (int ct = 0; ct < 4; ++ct)
#pragma unroll
      for (int reg = 0; reg < 4; ++reg) {
        const float p = __builtin_amdgcn_exp2f(accs[ct][reg]);
        l_i[reg] += p;
        Ps[(w * 16 + q * 4 + reg) * 72 + ct * 16 + ln] = f2bf(p);
      }

    // O += P @ V
#pragma unroll
    for (int ks2 = 0; ks2 < 2; ++ks2) {
      const short8 pa = *(const short8*)&Ps[(w * 16 + ln) * 72 + ks2 * 32 + q * 8];
#pragma unroll
      for (int nt = 0; nt < 4; ++nt) {
        const short8 bv = *(const short8*)&vg[(size_t)(nt * 16 + ln) * SEQ +
                                              kt * 64 + ks2 * 32 + q * 8];
        acc_o[nt] = __builtin_amdgcn_mfma_f32_16x16x32_bf16(pa, bv, acc_o[nt], 0, 0, 0);
      }
    }
  }

  // additive partial merge: atomicAdd into zeroed PO / Lb (2-operand, exact)
#pragma unroll
  for (int reg = 0; reg < 4; ++reg) {
    float l = l_i[reg];
    l += __shfl_xor(l, 1, 16);
    l += __shfl_xor(l, 2, 16);
    l += __shfl_xor(l, 4, 16);
    l += __shfl_xor(l, 8, 16);
    if (ln == 0) atomicAdd(&Lb[bh * SEQ + qt * 64 + w * 16 + q * 4 + reg], l);
  }
#pragma unroll
  for (int nt = 0; nt < 4; ++nt)
#pragma unroll
    for (int reg = 0; reg < 4; ++reg) {
      const int s = qt * 64 + w * 16 + q * 4 + reg;
      atomicAdd(&PO[((size_t)bh * SEQ + s) * DH + nt * 16 + ln], acc_o[nt][reg]);
    }
}

// ---------------------------------------------------------------------------
// normalize partials -> bf16 aws [b*2048+s][h*64+d]
// ---------------------------------------------------------------------------
__global__ __launch_bounds__(256) void merge_reduce(const float4* __restrict__ PO4,
                                                    const float* __restrict__ Lb,
                                                    ushort* __restrict__ aws) {
  const int i = blockIdx.x * 256 + threadIdx.x;  // 0 .. 1M-1
  const int row = i >> 4, d4 = i & 15;
  const int bh = row >> 11, s = row & (SEQ - 1);
  const int b = bh >> 4, h = bh & 15;
  const float4 f = PO4[i];
  const float inv = 1.0f / Lb[row];
  ushort4 u = make_ushort4(f2bf(f.x * inv), f2bf(f.y * inv),
                           f2bf(f.z * inv), f2bf(f.w * inv));
  *(ushort4*)&aws[((size_t)b * SEQ + s) * DMODEL + h * DH + d4 * 4] = u;
}

// ---------------------------------------------------------------------------
// Output projection: out = aws[4096,1024] @ WoT^T + bo (fp32). 64x128 tile,
// BK=64, global_load_lds staging, 512 blocks.
// ---------------------------------------------------------------------------
__global__ __launch_bounds__(256) void mfma_gemm_out(const ushort* __restrict__ A,
                                                     const ushort* __restrict__ Bt,
                                                     const float* __restrict__ bias,
                                                     float* __restrict__ dst) {
  __shared__ __align__(16) ushort As[64 * 64];
  __shared__ __align__(16) ushort Bs[128 * 64];
  const int t = threadIdx.x;
  const int w = t >> 6, lane = t & 63, ln = lane & 15, q = lane >> 4;
  const int wm = w & 1, wn = w >> 1;
  const int row0 = blockIdx.y * 64, col0 = blockIdx.x * 128;
  const int sw = ln & 7;

  f32x4 acc[2][4];
#pragma unroll
  for (int i = 0; i < 2; ++i)
#pragma unroll
    for (int j = 0; j < 4; ++j) acc[i][j] = (f32x4){0.f, 0.f, 0.f, 0.f};

  for (int k0 = 0; k0 < DMODEL; k0 += 64) {
    __syncthreads();
#pragma unroll
    for (int rep = 0; rep < 2; ++rep) {
      const int u0 = rep * 256 + w * 64;
      const int u = u0 + lane;
      const int r = u >> 3, gl = (u & 7) ^ (r & 7);
      gld16(&A[(size_t)(row0 + r) * DMODEL + k0 + gl * 8], &As[u0 * 8]);
    }
#pragma unroll
    for (int rep = 0; rep < 4; ++rep) {
      const int u0 = rep * 256 + w * 64;
      const int u = u0 + lane;
      const int r = u >> 3, gl = (u & 7) ^ (r & 7);
      gld16(&Bt[(size_t)(col0 + r) * DMODEL + k0 + gl * 8], &Bs[u0 * 8]);
    }
    __syncthreads();
#pragma unroll
    for (int ks = 0; ks < 2; ++ks) {
      short8 af[2], bf[4];
#pragma unroll
      for (int rt = 0; rt < 2; ++rt)
        af[rt] = *(const short8*)&As[(wm * 32 + rt * 16 + ln) * 64 +
                                     (((ks * 4 + q) ^ sw) * 8)];
#pragma unroll
      for (int ct = 0; ct < 4; ++ct)
        bf[ct] = *(const short8*)&Bs[(wn * 64 + ct * 16 + ln) * 64 +
                                     (((ks * 4 + q) ^ sw) * 8)];
#pragma unroll
      for (int rt = 0; rt < 2; ++rt)
#pragma unroll
        for (int ct = 0; ct < 4; ++ct)
          acc[rt][ct] = __builtin_amdgcn_mfma_f32_16x16x32_bf16(af[rt], bf[ct],
                                                                acc[rt][ct], 0, 0, 0);
    }
  }

#pragma unroll
  for (int rt = 0; rt < 2; ++rt)
#pragma unroll
    for (int ct = 0; ct < 4; ++ct) {
      const int c = col0 + wn * 64 + ct * 16 + ln;
      const float bi = bias[c];
#pragma unroll
      for (int reg = 0; reg < 4; ++reg) {
        const int r = row0 + wm * 32 + rt * 16 + q * 4 + reg;
        dst[(size_t)r * DMODEL + c] = acc[rt][ct][reg] + bi;
      }
    }
}

extern "C" void kernel_launch(void* const* d_in, const int* in_sizes, int n_in,
                              void* d_out, int out_size, void* d_ws,
                              size_t ws_size, hipStream_t stream) {
  const float* patch = (const float*)d_in[0];
  const float* pixel = (const float*)d_in[1];
  const float* Wq = (const float*)d_in[2];
  const float* Wk = (const float*)d_in[3];
  const float* Wv = (const float*)d_in[4];
  const float* Wo = (const float*)d_in[5];
  const float* bo = (const float*)d_in[6];
  float* out = (float*)d_out;

  const size_t E = (size_t)2 * SEQ * DMODEL;  // 4,194,304
  const size_t W = (size_t)DMODEL * DMODEL;   // 1,048,576
  ushort* pb  = (ushort*)d_ws;      // patch bf16   (reused as PO after qkv)
  ushort* xb  = pb + E;             // pixel bf16   (part of PO region)
  ushort* wqt = xb + E;             // Wq^T*QSCALE  (reused as Lb after qkv)
  ushort* wkt = wqt + W;
  ushort* wvt = wkt + W;
  ushort* wot = wvt + W;            // live until mfma_gemm_out
  ushort* qws = wot + W;            // [bh][seq][64]
  ushort* kws = qws + E;            // [bh][seq][64]
  ushort* vws = kws + E;            // [bh][64][seq]
  ushort* aws = vws + E;            // [4096][1024]

  // PO overlays pb+xb (dead after qkv GEMM); Lb overlays wqt (dead after qkv)
  float* PO = (float*)pb;           // [32 bh][2048 s][64 d] fp32 = 16 MB
  float* Lb = (float*)wqt;          // [32 bh][2048 s] fp32 = 256 KB

  cast_bf16<<<dim3(E / 4 / 256, 1, 2), 256, 0, stream>>>(
      (const float4*)patch, (const float4*)pixel, (ushort4*)pb, (ushort4*)xb, E / 4);
  transpose_cast<<<dim3(32, 32, 4), dim3(32, 8), 0, stream>>>(
      Wq, Wk, Wv, Wo, wqt, wkt, wvt, wot);
  mfma_gemm_qkv<<<dim3(8, 32, 3), 256, 0, stream>>>(pb, xb, wqt, wkt, wvt,
                                                    qws, kws, vws);
  hipMemsetAsync(PO, 0, (size_t)32 * SEQ * DH * sizeof(float), stream);
  hipMemsetAsync(Lb, 0, (size_t)32 * SEQ * sizeof(float), stream);
  flash_mfma<<<dim3(32, 32, 2), 256, 0, stream>>>(qws, kws, vws, PO, Lb);
  merge_reduce<<<dim3((32 * SEQ * DH / 4) / 256), 256, 0, stream>>>(
      (const float4*)PO, Lb, aws);
  mfma_gemm_out<<<dim3(8, 64), 256, 0, stream>>>(aws, wot, bo, out);
}

// Round 5
// 219.711 us; speedup vs baseline: 5.7172x; 1.8048x over previous
//
#include <hip/hip_runtime.h>

#define SEQ 2048
#define DMODEL 1024
#define HEADS 16
#define DH 64
// fold (1/sqrt(64)) * log2(e) into Wq so scores arrive in exp2 domain
#define QSCALE 0.180336880f

typedef __attribute__((ext_vector_type(8))) short short8;
typedef __attribute__((ext_vector_type(4))) float f32x4;

__device__ __forceinline__ ushort f2bf(float x) {
  union { float f; unsigned u; } v; v.f = x;
  return (ushort)((v.u + 0x7fffu + ((v.u >> 16) & 1u)) >> 16);
}

// async global->LDS, 16B per lane. LDS dest = wave-uniform base + lane*16.
__device__ __forceinline__ void gld16(const ushort* g, ushort* l) {
  __builtin_amdgcn_global_load_lds(
      (const __attribute__((address_space(1))) unsigned int*)g,
      (__attribute__((address_space(3))) unsigned int*)l, 16, 0, 0);
}

// fragment-major index for Q/K [bh][s-block s>>4][kg d>>5][lane q*16+ln][j]
// s = token row, d = head-dim col. A wave's MFMA fragment = base + lane*16B.
__device__ __forceinline__ size_t qk_idx(int bh, int s, int d) {
  return ((((size_t)bh * (SEQ / 16) + (s >> 4)) * 2 + (d >> 5)) * 64 +
          ((d >> 3) & 3) * 16 + (s & 15)) * 8 + (d & 7);
}
// fragment-major index for V^T [bh][d-block d>>4][s-group s>>5][lane][j]
__device__ __forceinline__ size_t v_idx(int bh, int s, int d) {
  return ((((size_t)bh * 4 + (d >> 4)) * (SEQ / 32) + (s >> 5)) * 64 +
          ((s >> 3) & 3) * 16 + (d & 15)) * 8 + (s & 7);
}

// ---------------------------------------------------------------------------
// fp32 -> bf16 cast; z picks (patch, pixel)
// ---------------------------------------------------------------------------
__global__ __launch_bounds__(256) void cast_bf16(const float4* __restrict__ in0,
                                                 const float4* __restrict__ in1,
                                                 ushort4* __restrict__ out0,
                                                 ushort4* __restrict__ out1, int n4) {
  const float4* in = blockIdx.z ? in1 : in0;
  ushort4* out = blockIdx.z ? out1 : out0;
  int i = blockIdx.x * 256 + threadIdx.x;
  if (i < n4) {
    float4 f = in[i];
    out[i] = make_ushort4(f2bf(f.x), f2bf(f.y), f2bf(f.z), f2bf(f.w));
  }
}

// ---------------------------------------------------------------------------
// W [K][N] fp32 -> Wt [N][K] bf16 (*QSCALE for z==0), z picks Wq/Wk/Wv/Wo
// ---------------------------------------------------------------------------
__global__ __launch_bounds__(256) void transpose_cast(
    const float* __restrict__ W0, const float* __restrict__ W1,
    const float* __restrict__ W2, const float* __restrict__ W3,
    ushort* __restrict__ O0, ushort* __restrict__ O1,
    ushort* __restrict__ O2, ushort* __restrict__ O3) {
  __shared__ float tile[32][33];
  const int z = blockIdx.z;
  const float* in = z == 0 ? W0 : z == 1 ? W1 : z == 2 ? W2 : W3;
  ushort* out = z == 0 ? O0 : z == 1 ? O1 : z == 2 ? O2 : O3;
  const float scale = z == 0 ? QSCALE : 1.0f;
  const int tx = threadIdx.x, ty = threadIdx.y;
  const int n0 = blockIdx.x * 32, k0 = blockIdx.y * 32;
#pragma unroll
  for (int i = 0; i < 4; ++i)
    tile[ty + i * 8][tx] = in[(size_t)(k0 + ty + i * 8) * DMODEL + n0 + tx];
  __syncthreads();
#pragma unroll
  for (int i = 0; i < 4; ++i)
    out[(size_t)(n0 + ty + i * 8) * DMODEL + k0 + tx] =
        f2bf(tile[tx][ty + i * 8] * scale);
}

// ---------------------------------------------------------------------------
// Fused Q/K/V projection GEMM, global_load_lds(16B) staging, XOR-swizzled on
// the GLOBAL side. 128x128 tile, BK=64, 4 waves. Epilogues scatter to the
// fragment-major layouts consumed by flash_mfma.
// ---------------------------------------------------------------------------
__global__ __launch_bounds__(256) void mfma_gemm_qkv(
    const ushort* __restrict__ pb, const ushort* __restrict__ xb,
    const ushort* __restrict__ wqt, const ushort* __restrict__ wkt,
    const ushort* __restrict__ wvt, ushort* __restrict__ qws,
    ushort* __restrict__ kws, ushort* __restrict__ vws) {
  __shared__ __align__(16) ushort As[128 * 64];
  __shared__ __align__(16) ushort Bs[128 * 64];
  const int z = blockIdx.z;
  const ushort* A = (z == 0) ? pb : xb;
  const ushort* Bt = (z == 0) ? wqt : (z == 1) ? wkt : wvt;

  const int t = threadIdx.x;
  const int w = t >> 6, lane = t & 63, ln = lane & 15, q = lane >> 4;
  const int wm = w & 1, wn = w >> 1;
  const int row0 = blockIdx.y * 128, col0 = blockIdx.x * 128;
  const int sw = ln & 7;

  f32x4 acc[4][4];
#pragma unroll
  for (int i = 0; i < 4; ++i)
#pragma unroll
    for (int j = 0; j < 4; ++j) acc[i][j] = (f32x4){0.f, 0.f, 0.f, 0.f};

  for (int k0 = 0; k0 < DMODEL; k0 += 64) {
    __syncthreads();  // prior frag reads done
#pragma unroll
    for (int rep = 0; rep < 4; ++rep) {
      const int u0 = rep * 256 + w * 64;
      const int u = u0 + lane;
      const int r = u >> 3, gl = (u & 7) ^ (r & 7);
      gld16(&A[(size_t)(row0 + r) * DMODEL + k0 + gl * 8], &As[u0 * 8]);
      gld16(&Bt[(size_t)(col0 + r) * DMODEL + k0 + gl * 8], &Bs[u0 * 8]);
    }
    __syncthreads();  // vmcnt drain
#pragma unroll
    for (int ks = 0; ks < 2; ++ks) {
      short8 af[4], bf[4];
#pragma unroll
      for (int rt = 0; rt < 4; ++rt)
        af[rt] = *(const short8*)&As[(wm * 64 + rt * 16 + ln) * 64 +
                                     (((ks * 4 + q) ^ sw) * 8)];
#pragma unroll
      for (int ct = 0; ct < 4; ++ct)
        bf[ct] = *(const short8*)&Bs[(wn * 64 + ct * 16 + ln) * 64 +
                                     (((ks * 4 + q) ^ sw) * 8)];
#pragma unroll
      for (int rt = 0; rt < 4; ++rt)
#pragma unroll
        for (int ct = 0; ct < 4; ++ct)
          acc[rt][ct] = __builtin_amdgcn_mfma_f32_16x16x32_bf16(af[rt], bf[ct],
                                                                acc[rt][ct], 0, 0, 0);
    }
  }

  if (z < 2) {
    ushort* dst = z == 0 ? qws : kws;
#pragma unroll
    for (int rt = 0; rt < 4; ++rt)
#pragma unroll
      for (int ct = 0; ct < 4; ++ct) {
        const int c = col0 + wn * 64 + ct * 16 + ln;
        const int h = c >> 6, d = c & 63;
#pragma unroll
        for (int reg = 0; reg < 4; ++reg) {
          const int r = row0 + wm * 64 + rt * 16 + q * 4 + reg;
          const int b = r >> 11, s = r & (SEQ - 1);
          dst[qk_idx(b * HEADS + h, s, d)] = f2bf(acc[rt][ct][reg]);
        }
      }
  } else {
#pragma unroll
    for (int rt = 0; rt < 4; ++rt)
#pragma unroll
      for (int ct = 0; ct < 4; ++ct) {
        const int c = col0 + wn * 64 + ct * 16 + ln;
        const int h = c >> 6, d = c & 63;
        const int r0 = row0 + wm * 64 + rt * 16 + q * 4;
        const int b = r0 >> 11, s0 = r0 & (SEQ - 1);
        ushort4 u4 = make_ushort4(f2bf(acc[rt][ct][0]), f2bf(acc[rt][ct][1]),
                                  f2bf(acc[rt][ct][2]), f2bf(acc[rt][ct][3]));
        // regs are 4 consecutive s -> consecutive j in v_idx (j0 = s0&7 in {0,4})
        *(ushort4*)&vws[v_idx(b * HEADS + h, s0, d)] = u4;
      }
  }
}

// ---------------------------------------------------------------------------
// Flash attention: full K-sweep per wave, zero in-loop barriers, no atomics.
// All Q/K/V fragment loads are single coalesced global_load_dwordx4 (the
// buffers are fragment-major). Wave = 16 Q rows; block = 4 waves = 64 rows.
// Grid (32 qt, 32 bh) = 1024 blocks = 4 blocks/CU -> 16 waves/CU.
// ---------------------------------------------------------------------------
__global__ __launch_bounds__(256) void flash_mfma(const ushort* __restrict__ Qg,
                                                  const ushort* __restrict__ Kg,
                                                  const ushort* __restrict__ Vg,
                                                  ushort* __restrict__ Og) {
  __shared__ __align__(16) ushort Ps[64 * 72];

  const int t = threadIdx.x;
  const int w = t >> 6, lane = t & 63, ln = lane & 15, q = lane >> 4;
  const int qt = blockIdx.x;   // 0..31 (64-row Q tile)
  const int bh = blockIdx.y;   // 0..31

  const ushort* qg = Qg + (size_t)bh * SEQ * DH;
  const ushort* kg = Kg + (size_t)bh * SEQ * DH;
  const ushort* vg = Vg + (size_t)bh * DH * SEQ;

  // Q A-fragments, coalesced: block rb = qt*4 + w, lane*16B
  short8 qf[2];
#pragma unroll
  for (int ks = 0; ks < 2; ++ks)
    qf[ks] = *(const short8*)&qg[((((size_t)(qt * 4 + w)) * 2 + ks) * 64 + lane) * 8];

  float l_i[4] = {0.f, 0.f, 0.f, 0.f};
  f32x4 acc_o[4];
#pragma unroll
  for (int nt = 0; nt < 4; ++nt) acc_o[nt] = (f32x4){0.f, 0.f, 0.f, 0.f};

  for (int kt = 0; kt < SEQ / 64; ++kt) {
    // S = Q @ K^T (wave: 16 x 64); K frags coalesced (rb = kt*4+ct, kg = ks)
    f32x4 accs[4];
#pragma unroll
    for (int ct = 0; ct < 4; ++ct) accs[ct] = (f32x4){0.f, 0.f, 0.f, 0.f};
#pragma unroll
    for (int ks = 0; ks < 2; ++ks) {
      short8 bfr[4];
#pragma unroll
      for (int ct = 0; ct < 4; ++ct)
        bfr[ct] = *(const short8*)&kg[((((size_t)(kt * 4 + ct)) * 2 + ks) * 64 +
                                       lane) * 8];
#pragma unroll
      for (int ct = 0; ct < 4; ++ct)
        accs[ct] = __builtin_amdgcn_mfma_f32_16x16x32_bf16(qf[ks], bfr[ct],
                                                           accs[ct], 0, 0, 0);
    }

    // V^T frags for this kt (independent of S -> compiler can overlap)
    short8 bv[2][4];
#pragma unroll
    for (int ks2 = 0; ks2 < 2; ++ks2)
#pragma unroll
      for (int nt = 0; nt < 4; ++nt)
        bv[ks2][nt] = *(const short8*)&vg[(((size_t)nt * (SEQ / 32) + kt * 2 + ks2) *
                                           64 + lane) * 8];

    // p = 2^s (Q pre-scaled), lane-partial l, P -> wave-private LDS rows
#pragma unroll
    for (int ct = 0; ct < 4; ++ct)
#pragma unroll
      for (int reg = 0; reg < 4; ++reg) {
        const float p = __builtin_amdgcn_exp2f(accs[ct][reg]);
        l_i[reg] += p;
        Ps[(w * 16 + q * 4 + reg) * 72 + ct * 16 + ln] = f2bf(p);
      }

    // O += P @ V
#pragma unroll
    for (int ks2 = 0; ks2 < 2; ++ks2) {
      const short8 pa = *(const short8*)&Ps[(w * 16 + ln) * 72 + ks2 * 32 + q * 8];
#pragma unroll
      for (int nt = 0; nt < 4; ++nt)
        acc_o[nt] = __builtin_amdgcn_mfma_f32_16x16x32_bf16(pa, bv[ks2][nt],
                                                            acc_o[nt], 0, 0, 0);
    }
  }

  // epilogue: reduce l over the quad's 16 lanes, normalize, write aws bf16
  const int b = bh >> 4, h = bh & 15;
#pragma unroll
  for (int reg = 0; reg < 4; ++reg) {
    float l = l_i[reg];
    l += __shfl_xor(l, 1, 16);
    l += __shfl_xor(l, 2, 16);
    l += __shfl_xor(l, 4, 16);
    l += __shfl_xor(l, 8, 16);
    const float inv = 1.0f / l;
    const int s = qt * 64 + w * 16 + q * 4 + reg;
#pragma unroll
    for (int nt = 0; nt < 4; ++nt)
      Og[(size_t)(b * SEQ + s) * DMODEL + h * DH + nt * 16 + ln] =
          f2bf(acc_o[nt][reg] * inv);
  }
}

// ---------------------------------------------------------------------------
// Output projection: out = aws[4096,1024] @ WoT^T + bo (fp32). 64x128 tile,
// BK=64, global_load_lds staging, 512 blocks.
// ---------------------------------------------------------------------------
__global__ __launch_bounds__(256) void mfma_gemm_out(const ushort* __restrict__ A,
                                                     const ushort* __restrict__ Bt,
                                                     const float* __restrict__ bias,
                                                     float* __restrict__ dst) {
  __shared__ __align__(16) ushort As[64 * 64];
  __shared__ __align__(16) ushort Bs[128 * 64];
  const int t = threadIdx.x;
  const int w = t >> 6, lane = t & 63, ln = lane & 15, q = lane >> 4;
  const int wm = w & 1, wn = w >> 1;
  const int row0 = blockIdx.y * 64, col0 = blockIdx.x * 128;
  const int sw = ln & 7;

  f32x4 acc[2][4];
#pragma unroll
  for (int i = 0; i < 2; ++i)
#pragma unroll
    for (int j = 0; j < 4; ++j) acc[i][j] = (f32x4){0.f, 0.f, 0.f, 0.f};

  for (int k0 = 0; k0 < DMODEL; k0 += 64) {
    __syncthreads();
#pragma unroll
    for (int rep = 0; rep < 2; ++rep) {
      const int u0 = rep * 256 + w * 64;
      const int u = u0 + lane;
      const int r = u >> 3, gl = (u & 7) ^ (r & 7);
      gld16(&A[(size_t)(row0 + r) * DMODEL + k0 + gl * 8], &As[u0 * 8]);
    }
#pragma unroll
    for (int rep = 0; rep < 4; ++rep) {
      const int u0 = rep * 256 + w * 64;
      const int u = u0 + lane;
      const int r = u >> 3, gl = (u & 7) ^ (r & 7);
      gld16(&Bt[(size_t)(col0 + r) * DMODEL + k0 + gl * 8], &Bs[u0 * 8]);
    }
    __syncthreads();
#pragma unroll
    for (int ks = 0; ks < 2; ++ks) {
      short8 af[2], bf[4];
#pragma unroll
      for (int rt = 0; rt < 2; ++rt)
        af[rt] = *(const short8*)&As[(wm * 32 + rt * 16 + ln) * 64 +
                                     (((ks * 4 + q) ^ sw) * 8)];
#pragma unroll
      for (int ct = 0; ct < 4; ++ct)
        bf[ct] = *(const short8*)&Bs[(wn * 64 + ct * 16 + ln) * 64 +
                                     (((ks * 4 + q) ^ sw) * 8)];
#pragma unroll
      for (int rt = 0; rt < 2; ++rt)
#pragma unroll
        for (int ct = 0; ct < 4; ++ct)
          acc[rt][ct] = __builtin_amdgcn_mfma_f32_16x16x32_bf16(af[rt], bf[ct],
                                                                acc[rt][ct], 0, 0, 0);
    }
  }

#pragma unroll
  for (int rt = 0; rt < 2; ++rt)
#pragma unroll
    for (int ct = 0; ct < 4; ++ct) {
      const int c = col0 + wn * 64 + ct * 16 + ln;
      const float bi = bias[c];
#pragma unroll
      for (int reg = 0; reg < 4; ++reg) {
        const int r = row0 + wm * 32 + rt * 16 + q * 4 + reg;
        dst[(size_t)r * DMODEL + c] = acc[rt][ct][reg] + bi;
      }
    }
}

extern "C" void kernel_launch(void* const* d_in, const int* in_sizes, int n_in,
                              void* d_out, int out_size, void* d_ws,
                              size_t ws_size, hipStream_t stream) {
  const float* patch = (const float*)d_in[0];
  const float* pixel = (const float*)d_in[1];
  const float* Wq = (const float*)d_in[2];
  const float* Wk = (const float*)d_in[3];
  const float* Wv = (const float*)d_in[4];
  const float* Wo = (const float*)d_in[5];
  const float* bo = (const float*)d_in[6];
  float* out = (float*)d_out;

  const size_t E = (size_t)2 * SEQ * DMODEL;  // 4,194,304
  const size_t W = (size_t)DMODEL * DMODEL;   // 1,048,576
  ushort* pb  = (ushort*)d_ws;      // patch bf16
  ushort* xb  = pb + E;             // pixel bf16
  ushort* wqt = xb + E;             // Wq^T * QSCALE bf16 [N][K]
  ushort* wkt = wqt + W;
  ushort* wvt = wkt + W;
  ushort* wot = wvt + W;
  ushort* qws = wot + W;            // Q fragment-major
  ushort* kws = qws + E;            // K fragment-major
  ushort* vws = kws + E;            // V^T fragment-major
  ushort* aws = vws + E;            // [4096][1024] row-major bf16

  cast_bf16<<<dim3(E / 4 / 256, 1, 2), 256, 0, stream>>>(
      (const float4*)patch, (const float4*)pixel, (ushort4*)pb, (ushort4*)xb, E / 4);
  transpose_cast<<<dim3(32, 32, 4), dim3(32, 8), 0, stream>>>(
      Wq, Wk, Wv, Wo, wqt, wkt, wvt, wot);
  mfma_gemm_qkv<<<dim3(8, 32, 3), 256, 0, stream>>>(pb, xb, wqt, wkt, wvt,
                                                    qws, kws, vws);
  flash_mfma<<<dim3(32, 32), 256, 0, stream>>>(qws, kws, vws, aws);
  mfma_gemm_out<<<dim3(8, 64), 256, 0, stream>>>(aws, wot, bo, out);
}